// Round 2
// baseline (85911.584 us; speedup 1.0000x reference)
//
#include <hip/hip_runtime.h>
#include <math.h>

#define E_DIM 1024
#define T_SEQ 2048
#define NH 16
#define DHEAD 64
#define NB 4
#define NLAYER 8

// ============================ embedding ============================
__global__ __launch_bounds__(256) void embed_kernel(const int* __restrict__ tokens,
    const float* __restrict__ emb, const float* __restrict__ pos, float* __restrict__ x) {
  int idx = blockIdx.x * 256 + threadIdx.x;      // over B*T*E = 8388608
  int bt = idx >> 10;
  int e  = idx & 1023;
  int t  = bt & (T_SEQ - 1);
  int tok = tokens[bt];
  x[idx] = emb[tok * E_DIM + e] + pos[t * E_DIM + e];
}

// ============================ layernorm ============================
// one block (256 thr) per row of 1024
__global__ __launch_bounds__(256) void ln_kernel(const float* __restrict__ x,
    const float* __restrict__ g, const float* __restrict__ b, float* __restrict__ out) {
  __shared__ float s1[4], s2[4];
  int row = blockIdx.x;
  const float4* xr = (const float4*)(x + (size_t)row * E_DIM);
  float4 xv = xr[threadIdx.x];
  float s = xv.x + xv.y + xv.z + xv.w;
  float q = xv.x*xv.x + xv.y*xv.y + xv.z*xv.z + xv.w*xv.w;
  #pragma unroll
  for (int off = 32; off; off >>= 1) {
    s += __shfl_xor(s, off, 64);
    q += __shfl_xor(q, off, 64);
  }
  int lane = threadIdx.x & 63, wid = threadIdx.x >> 6;
  if (lane == 0) { s1[wid] = s; s2[wid] = q; }
  __syncthreads();
  float mean = (s1[0] + s1[1] + s1[2] + s1[3]) * (1.0f / E_DIM);
  float ms   = (s2[0] + s2[1] + s2[2] + s2[3]) * (1.0f / E_DIM);
  float rstd = rsqrtf(ms - mean * mean + 1e-5f);
  float4 gv = ((const float4*)g)[threadIdx.x];
  float4 bv = ((const float4*)b)[threadIdx.x];
  float4 ov;
  ov.x = (xv.x - mean) * rstd * gv.x + bv.x;
  ov.y = (xv.y - mean) * rstd * gv.y + bv.y;
  ov.z = (xv.z - mean) * rstd * gv.z + bv.z;
  ov.w = (xv.w - mean) * rstd * gv.w + bv.w;
  ((float4*)(out + (size_t)row * E_DIM))[threadIdx.x] = ov;
}

// ============================ generic strided GEMM ============================
// C[m,n] = alpha * sum_k A[m,k]*B[k,n]  (+bias[n]) (relu) (+res[m,n])
// m-addressing: (m>>11)*sXb + (m&2047)*sXt   (row blocks of T=2048)
// n/k col-addressing: (i>>6)*sXh + (i&63)*sXd (col blocks of 64 = one head)
// This one kernel handles plain row-major, head-blocked [H,E,DH] weights, and
// [B,H,T,DH] scatter/gather without any transpose kernels.
struct GemmP {
  const float* A; const float* B; float* C;
  const float* bias; const float* res;
  long sAb, sAt, sAh, sAd;
  long sBkb, sBk, sBnb, sBn;
  long sCb, sCt, sCnb, sCn;
  int K; float alpha; int relu;
};

__global__ __launch_bounds__(256) void gemm_f32(GemmP p) {
  __shared__ float As[16][132];   // [k][m]  (132: 16B-aligned rows, 2-way-max banks)
  __shared__ float Bs[16][132];   // [k][n]
  const int tid = threadIdx.x;
  const int bm = blockIdx.y * 128;
  const int bn = blockIdx.x * 128;
  const int tx = tid & 15, ty = tid >> 4;
  float acc[8][8];
  #pragma unroll
  for (int i = 0; i < 8; ++i)
    #pragma unroll
    for (int j = 0; j < 8; ++j) acc[i][j] = 0.f;

  for (int k0 = 0; k0 < p.K; k0 += 16) {
    #pragma unroll
    for (int j = 0; j < 8; ++j) {            // A tile: 128m x 16k
      int lin = tid + 256 * j;
      int mo = lin >> 4, ko = lin & 15;
      int m = bm + mo, kk = k0 + ko;
      As[ko][mo] = p.A[(long)(m >> 11) * p.sAb + (long)(m & 2047) * p.sAt
                     + (long)(kk >> 6) * p.sAh + (long)(kk & 63) * p.sAd];
    }
    #pragma unroll
    for (int j = 0; j < 8; ++j) {            // B tile: 16k x 128n
      int lin = tid + 256 * j;
      int ko = lin >> 7, no = lin & 127;
      int kk = k0 + ko, n = bn + no;
      Bs[ko][no] = p.B[(long)(kk >> 11) * p.sBkb + (long)(kk & 2047) * p.sBk
                     + (long)(n >> 6) * p.sBnb + (long)(n & 63) * p.sBn];
    }
    __syncthreads();
    #pragma unroll
    for (int kk = 0; kk < 16; ++kk) {
      float a[8], b[8];
      *(float4*)&a[0] = *(const float4*)&As[kk][ty * 8];
      *(float4*)&a[4] = *(const float4*)&As[kk][ty * 8 + 4];
      *(float4*)&b[0] = *(const float4*)&Bs[kk][tx * 8];
      *(float4*)&b[4] = *(const float4*)&Bs[kk][tx * 8 + 4];
      #pragma unroll
      for (int i = 0; i < 8; ++i)
        #pragma unroll
        for (int j = 0; j < 8; ++j)
          acc[i][j] = fmaf(a[i], b[j], acc[i][j]);
    }
    __syncthreads();
  }
  #pragma unroll
  for (int i = 0; i < 8; ++i) {
    int m = bm + ty * 8 + i;
    long mb = (long)(m >> 11) * p.sCb + (long)(m & 2047) * p.sCt;
    #pragma unroll
    for (int j = 0; j < 8; ++j) {
      int n = bn + tx * 8 + j;
      long ca = mb + (long)(n >> 6) * p.sCnb + (long)(n & 63) * p.sCn;
      float v = p.alpha * acc[i][j];
      if (p.bias) v += p.bias[n];
      if (p.relu) v = fmaxf(v, 0.f);
      if (p.res)  v += p.res[ca];
      p.C[ca] = v;
    }
  }
}

// ============================ flash attention (f32) ============================
// q,k,v: [B,H,T,DH]; out att: [B,H,T,DH]. Non-causal, online softmax.
// block = 256 thr (4 waves), 16 t-rows per block (4 per wave), K/V tiled 64 keys.
__global__ __launch_bounds__(256) void attn_kernel(const float* __restrict__ q,
    const float* __restrict__ k, const float* __restrict__ v, float* __restrict__ att) {
  __shared__ float ks[64][66];   // [d][s']   (transposed on LDS store)
  __shared__ float vs[64][64];   // [s'][d]
  __shared__ float qs[16][64];
  __shared__ float ps[4][64];
  int bh = blockIdx.x >> 7;                 // 128 t-blocks per (b,h)
  int r0 = (blockIdx.x & 127) * 16;
  int tid = threadIdx.x;
  int lane = tid & 63, wid = tid >> 6;
  const float* qb = q + (size_t)bh * T_SEQ * DHEAD;
  const float* kb = k + (size_t)bh * T_SEQ * DHEAD;
  const float* vb = v + (size_t)bh * T_SEQ * DHEAD;

  #pragma unroll
  for (int j = 0; j < 4; ++j) {             // 16 rows x 64
    int lin = tid + 256 * j;
    qs[lin >> 6][lin & 63] = qb[(size_t)(r0 + (lin >> 6)) * DHEAD + (lin & 63)];
  }
  float mrun[4], lrun[4], o[4];
  #pragma unroll
  for (int r = 0; r < 4; ++r) { mrun[r] = -3.0e38f; lrun[r] = 0.f; o[r] = 0.f; }

  for (int s0 = 0; s0 < T_SEQ; s0 += 64) {
    __syncthreads();
    #pragma unroll
    for (int j = 0; j < 16; ++j) {          // stage K (transposed) + V tiles
      int lin = tid + 256 * j;
      int s = lin >> 6, d = lin & 63;
      float kvld = kb[(size_t)(s0 + s) * DHEAD + d];
      ks[d][s] = kvld;
      vs[s][d] = vb[(size_t)(s0 + s) * DHEAD + d];
    }
    __syncthreads();
    #pragma unroll
    for (int r = 0; r < 4; ++r) {
      int row = wid * 4 + r;
      // score for key (s0+lane): dot over d
      float c0 = 0, c1 = 0, c2 = 0, c3 = 0;
      #pragma unroll
      for (int d = 0; d < 64; d += 4) {
        c0 = fmaf(qs[row][d + 0], ks[d + 0][lane], c0);
        c1 = fmaf(qs[row][d + 1], ks[d + 1][lane], c1);
        c2 = fmaf(qs[row][d + 2], ks[d + 2][lane], c2);
        c3 = fmaf(qs[row][d + 3], ks[d + 3][lane], c3);
      }
      float sc = (c0 + c1) + (c2 + c3);
      float bmax = sc;
      #pragma unroll
      for (int off = 32; off; off >>= 1) bmax = fmaxf(bmax, __shfl_xor(bmax, off, 64));
      float mn = fmaxf(mrun[r], bmax);
      float pexp = __expf(sc - mn);
      float sp = pexp;
      #pragma unroll
      for (int off = 32; off; off >>= 1) sp += __shfl_xor(sp, off, 64);
      float corr = __expf(mrun[r] - mn);
      lrun[r] = lrun[r] * corr + sp;
      mrun[r] = mn;
      ps[wid][lane] = pexp;                  // wave-private, lockstep-safe
      float t0 = 0, t1 = 0, t2 = 0, t3 = 0;
      #pragma unroll
      for (int s1 = 0; s1 < 64; s1 += 4) {
        t0 = fmaf(ps[wid][s1 + 0], vs[s1 + 0][lane], t0);
        t1 = fmaf(ps[wid][s1 + 1], vs[s1 + 1][lane], t1);
        t2 = fmaf(ps[wid][s1 + 2], vs[s1 + 2][lane], t2);
        t3 = fmaf(ps[wid][s1 + 3], vs[s1 + 3][lane], t3);
      }
      o[r] = o[r] * corr + ((t0 + t1) + (t2 + t3));
    }
  }
  #pragma unroll
  for (int r = 0; r < 4; ++r) {
    int row = wid * 4 + r;
    att[((size_t)bh * T_SEQ + r0 + row) * DHEAD + lane] = o[r] / lrun[r];
  }
}

// ============================ head: [8192,1024] @ [1024,2] + bu ============================
__global__ __launch_bounds__(256) void head_kernel(const float* __restrict__ h,
    const float* __restrict__ Wu, const float* __restrict__ bu, float* __restrict__ out) {
  __shared__ float sm[8];
  int row = blockIdx.x;
  const float* hr = h + (size_t)row * E_DIM;
  float a0 = 0.f, a1 = 0.f;
  for (int i = threadIdx.x; i < E_DIM; i += 256) {
    float hv = hr[i];
    a0 = fmaf(hv, Wu[i * 2 + 0], a0);
    a1 = fmaf(hv, Wu[i * 2 + 1], a1);
  }
  #pragma unroll
  for (int off = 32; off; off >>= 1) {
    a0 += __shfl_xor(a0, off, 64);
    a1 += __shfl_xor(a1, off, 64);
  }
  int lane = threadIdx.x & 63, wid = threadIdx.x >> 6;
  if (lane == 0) { sm[wid] = a0; sm[4 + wid] = a1; }
  __syncthreads();
  if (threadIdx.x == 0) {
    out[row * 2 + 0] = sm[0] + sm[1] + sm[2] + sm[3] + bu[0];
    out[row * 2 + 1] = sm[4] + sm[5] + sm[6] + sm[7] + bu[1];
  }
}

// ============================ launcher ============================
static inline void launch_gemm(hipStream_t stream,
    const float* A, long sAb, long sAt, long sAh, long sAd,
    const float* B, long sBkb, long sBk, long sBnb, long sBn,
    float* C, long sCb, long sCt, long sCnb, long sCn,
    const float* bias, const float* res, int N, int K, float alpha, int relu) {
  GemmP p;
  p.A = A; p.B = B; p.C = C; p.bias = bias; p.res = res;
  p.sAb = sAb; p.sAt = sAt; p.sAh = sAh; p.sAd = sAd;
  p.sBkb = sBkb; p.sBk = sBk; p.sBnb = sBnb; p.sBn = sBn;
  p.sCb = sCb; p.sCt = sCt; p.sCnb = sCnb; p.sCn = sCn;
  p.K = K; p.alpha = alpha; p.relu = relu;
  dim3 grid(N / 128, (NB * T_SEQ) / 128);
  gemm_f32<<<grid, 256, 0, stream>>>(p);
}

extern "C" void kernel_launch(void* const* d_in, const int* in_sizes, int n_in,
                              void* d_out, int out_size, void* d_ws, size_t ws_size,
                              hipStream_t stream) {
  const int*   tokens = (const int*)d_in[0];
  const float* emb_w  = (const float*)d_in[1];
  const float* pos_w  = (const float*)d_in[2];
  const float* Wq     = (const float*)d_in[3];
  const float* Wk     = (const float*)d_in[4];
  const float* Wv     = (const float*)d_in[5];
  const float* Wo     = (const float*)d_in[6];
  const float* ln1_g  = (const float*)d_in[7];
  const float* ln1_b  = (const float*)d_in[8];
  const float* W1     = (const float*)d_in[9];
  const float* b1     = (const float*)d_in[10];
  const float* W2     = (const float*)d_in[11];
  const float* b2     = (const float*)d_in[12];
  const float* ln2_g  = (const float*)d_in[13];
  const float* ln2_b  = (const float*)d_in[14];
  const float* lnf_g  = (const float*)d_in[15];
  const float* lnf_b  = (const float*)d_in[16];
  const float* Wu     = (const float*)d_in[17];
  const float* bu     = (const float*)d_in[18];
  float* out = (float*)d_out;

  // workspace layout (floats):
  //  X   : 8388608   [B,T,E]
  //  Hb  : 8388608   LN output; also reused as attention output (att)
  //  BIG : 33554432  q/k/v live here; MLP hidden overwrites them (dead by then)
  float* ws  = (float*)d_ws;
  float* X   = ws;
  float* Hb  = ws + 8388608;
  float* BIG = ws + 16777216;
  float* Q   = BIG;
  float* Kb  = BIG + 8388608;
  float* V   = BIG + 16777216;
  float* FFH = BIG;

  const float scale = 0.022097086912079608f;   // 1/sqrt(2048)

  embed_kernel<<<32768, 256, 0, stream>>>(tokens, emb_w, pos_w, X);

  // stride sets
  const long A_h[4]   = {2097152, 1024, 64, 1};       // h as [8192,1024] row-major
  const long A_att[4] = {2097152, 64, 131072, 1};     // att [B,H,T,DH], k = h*64+d
  const long A_ffh[4] = {8388608, 4096, 64, 1};       // ffh [8192,4096]
  const long B_qkv[4] = {0, 64, 65536, 1};            // [H,E,DH] head-blocked
  const long B_wo[4]  = {0, 1024, 64, 1};             // [E,E]
  const long B_w1[4]  = {0, 4096, 64, 1};             // [E,4E]
  const long B_w2[4]  = {2097152, 1024, 64, 1};       // [4E,E]
  const long C_qv[4]  = {2097152, 64, 131072, 1};     // [B,H,T,DH]
  const long C_x[4]   = {2097152, 1024, 64, 1};       // [B,T,E]
  const long C_ffh[4] = {8388608, 4096, 64, 1};       // [8192,4096]

  for (int l = 0; l < NLAYER; ++l) {
    const float* Wq_l = Wq + (size_t)l * 1048576;
    const float* Wk_l = Wk + (size_t)l * 1048576;
    const float* Wv_l = Wv + (size_t)l * 1048576;
    const float* Wo_l = Wo + (size_t)l * 1048576;
    const float* W1_l = W1 + (size_t)l * 4194304;
    const float* W2_l = W2 + (size_t)l * 4194304;

    ln_kernel<<<8192, 256, 0, stream>>>(X, ln1_g + l * 1024, ln1_b + l * 1024, Hb);

    launch_gemm(stream, Hb, A_h[0], A_h[1], A_h[2], A_h[3],
                Wq_l, B_qkv[0], B_qkv[1], B_qkv[2], B_qkv[3],
                Q, C_qv[0], C_qv[1], C_qv[2], C_qv[3],
                nullptr, nullptr, 1024, 1024, scale, 0);
    launch_gemm(stream, Hb, A_h[0], A_h[1], A_h[2], A_h[3],
                Wk_l, B_qkv[0], B_qkv[1], B_qkv[2], B_qkv[3],
                Kb, C_qv[0], C_qv[1], C_qv[2], C_qv[3],
                nullptr, nullptr, 1024, 1024, 1.0f, 0);
    launch_gemm(stream, Hb, A_h[0], A_h[1], A_h[2], A_h[3],
                Wv_l, B_qkv[0], B_qkv[1], B_qkv[2], B_qkv[3],
                V, C_qv[0], C_qv[1], C_qv[2], C_qv[3],
                nullptr, nullptr, 1024, 1024, 1.0f, 0);

    attn_kernel<<<8192, 256, 0, stream>>>(Q, Kb, V, Hb);   // att -> Hb (h is dead)

    launch_gemm(stream, Hb, A_att[0], A_att[1], A_att[2], A_att[3],
                Wo_l, B_wo[0], B_wo[1], B_wo[2], B_wo[3],
                X, C_x[0], C_x[1], C_x[2], C_x[3],
                nullptr, X, 1024, 1024, 1.0f, 0);

    ln_kernel<<<8192, 256, 0, stream>>>(X, ln2_g + l * 1024, ln2_b + l * 1024, Hb);

    launch_gemm(stream, Hb, A_h[0], A_h[1], A_h[2], A_h[3],
                W1_l, B_w1[0], B_w1[1], B_w1[2], B_w1[3],
                FFH, C_ffh[0], C_ffh[1], C_ffh[2], C_ffh[3],
                b1 + (size_t)l * 4096, nullptr, 4096, 1024, 1.0f, 1);

    launch_gemm(stream, FFH, A_ffh[0], A_ffh[1], A_ffh[2], A_ffh[3],
                W2_l, B_w2[0], B_w2[1], B_w2[2], B_w2[3],
                X, C_x[0], C_x[1], C_x[2], C_x[3],
                b2 + (size_t)l * 1024, X, 1024, 4096, 1.0f, 0);
  }

  ln_kernel<<<8192, 256, 0, stream>>>(X, lnf_g, lnf_b, Hb);
  head_kernel<<<8192, 256, 0, stream>>>(Hb, Wu, bu, out);
}

// Round 3
// 4374.334 us; speedup vs baseline: 19.6399x; 19.6399x over previous
//
#include <hip/hip_runtime.h>
#include <hip/hip_bf16.h>
#include <math.h>

#define E_DIM 1024
#define T_SEQ 2048
#define NH 16
#define DHEAD 64
#define NB 4
#define NLAYER 8

typedef __attribute__((ext_vector_type(8))) short bf16x8;
typedef __attribute__((ext_vector_type(4))) short short4v;
typedef __attribute__((ext_vector_type(4))) float f32x4;

static __device__ __forceinline__ short f2bf(float f) {
  union { __hip_bfloat16 h; short s; } u;
  u.h = __float2bfloat16(f);
  return u.s;
}
static __device__ __forceinline__ float bf2f(short s) {
  union { unsigned u; float f; } v;
  v.u = ((unsigned)(unsigned short)s) << 16;
  return v.f;
}

// ============================ embedding (f32) ============================
__global__ __launch_bounds__(256) void embed_kernel(const int* __restrict__ tokens,
    const float* __restrict__ emb, const float* __restrict__ pos, float* __restrict__ x) {
  int idx = blockIdx.x * 256 + threadIdx.x;
  int bt = idx >> 10;
  int e  = idx & 1023;
  int t  = bt & (T_SEQ - 1);
  int tok = tokens[bt];
  x[idx] = emb[tok * E_DIM + e] + pos[t * E_DIM + e];
}

// ============================ layernorm f32 -> bf16 ============================
__global__ __launch_bounds__(256) void ln_bf16_kernel(const float* __restrict__ x,
    const float* __restrict__ g, const float* __restrict__ b, short* __restrict__ out) {
  __shared__ float s1[4], s2[4];
  int row = blockIdx.x;
  const float4* xr = (const float4*)(x + (size_t)row * E_DIM);
  float4 xv = xr[threadIdx.x];
  float s = xv.x + xv.y + xv.z + xv.w;
  float q = xv.x*xv.x + xv.y*xv.y + xv.z*xv.z + xv.w*xv.w;
  #pragma unroll
  for (int off = 32; off; off >>= 1) {
    s += __shfl_xor(s, off, 64);
    q += __shfl_xor(q, off, 64);
  }
  int lane = threadIdx.x & 63, wid = threadIdx.x >> 6;
  if (lane == 0) { s1[wid] = s; s2[wid] = q; }
  __syncthreads();
  float mean = (s1[0] + s1[1] + s1[2] + s1[3]) * (1.0f / E_DIM);
  float ms   = (s2[0] + s2[1] + s2[2] + s2[3]) * (1.0f / E_DIM);
  float rstd = rsqrtf(ms - mean * mean + 1e-5f);
  float4 gv = ((const float4*)g)[threadIdx.x];
  float4 bv = ((const float4*)b)[threadIdx.x];
  short4v ov;
  ov.x = f2bf((xv.x - mean) * rstd * gv.x + bv.x);
  ov.y = f2bf((xv.y - mean) * rstd * gv.y + bv.y);
  ov.z = f2bf((xv.z - mean) * rstd * gv.z + bv.z);
  ov.w = f2bf((xv.w - mean) * rstd * gv.w + bv.w);
  *(short4v*)(out + (size_t)row * E_DIM + threadIdx.x * 4) = ov;
}

// ============================ cast+transpose f32[K][N] -> bf16[N][K] ============================
// grid: (K/32, N/32, BATCH), block (32,8)
__global__ void castT_kernel(const float* __restrict__ in, short* __restrict__ out,
                             int K, int N) {
  __shared__ float tile[32][33];
  int k0 = blockIdx.x * 32, n0 = blockIdx.y * 32;
  const float* ib = in + (size_t)blockIdx.z * K * N;
  short* ob = out + (size_t)blockIdx.z * N * K;
  int tx = threadIdx.x, ty = threadIdx.y;
  #pragma unroll
  for (int i = 0; i < 4; ++i)
    tile[ty + 8 * i][tx] = ib[(size_t)(k0 + ty + 8 * i) * N + n0 + tx];
  __syncthreads();
  #pragma unroll
  for (int i = 0; i < 4; ++i)
    ob[(size_t)(n0 + ty + 8 * i) * K + k0 + tx] = f2bf(tile[tx][ty + 8 * i]);
}

// ============================ bf16 MFMA GEMM ============================
// C[m,n] = alpha * sum_k A[m,k] * BT[n,k]  (+bias) (relu) (+res), strided addressing.
// 128x128 tile, BK=64, 4 waves each own a 64x64 quadrant (4x4 frags of 16x16).
// LDS XOR-swizzled (chunk ^= row&7) -> 2-way max conflicts on b128 ops.
struct GemmP {
  const short* A; const short* B; void* C;
  const float* bias; const float* res;
  long sAb, sAt, sAh;       // m>>11, m&2047, k>>6 (k&63 stride 1)
  long sBh, sBd;            // n>>6, n&63 (k stride 1)
  long sCb, sCt, sCh;       // m>>11, m&2047, n>>6 (n&63 stride 1)
  int K; float alpha; int relu; int cbf16; int hasbias; int hasres;
};

__global__ __launch_bounds__(256) void gemm_bf16(GemmP p) {
  __shared__ short As[128 * 64];
  __shared__ short Bs[128 * 64];
  const int t = threadIdx.x;
  const int lane = t & 63, wid = t >> 6;
  const int wr = wid >> 1, wc = wid & 1;
  const long bm = (long)blockIdx.y * 128, bn = (long)blockIdx.x * 128;

  // staging constants: thread t handles rows (c*32 + t>>3), chunk col t&7
  const int prow = t >> 3;
  const int pcol = t & 7;
  long aRow[4], bRow[4];
  int wIdx[4];
  #pragma unroll
  for (int c = 0; c < 4; ++c) {
    int r = c * 32 + prow;
    long gm = bm + r, gn = bn + r;
    aRow[c] = (gm >> 11) * p.sAb + (gm & 2047) * p.sAt;
    bRow[c] = (gn >> 6) * p.sBh + (gn & 63) * p.sBd;
    wIdx[c] = r * 64 + ((pcol ^ (r & 7)) << 3);
  }

  // fragment read offsets
  const int rA = lane & 15;
  const int g  = lane >> 4;
  int aOff[4][2], bOff[4][2];
  #pragma unroll
  for (int f = 0; f < 4; ++f) {
    int rowa = wr * 64 + f * 16 + rA;
    int rowb = wc * 64 + f * 16 + rA;
    #pragma unroll
    for (int kk = 0; kk < 2; ++kk) {
      aOff[f][kk] = rowa * 64 + (((g + kk * 4) ^ (rowa & 7)) << 3);
      bOff[f][kk] = rowb * 64 + (((g + kk * 4) ^ (rowb & 7)) << 3);
    }
  }

  f32x4 acc[4][4] = {};
  bf16x8 ra[4], rb[4];
  {
    long kc = (long)(pcol * 8);
    long ka = (kc >> 6) * p.sAh + (kc & 63);
    #pragma unroll
    for (int c = 0; c < 4; ++c) {
      ra[c] = *(const bf16x8*)(p.A + aRow[c] + ka);
      rb[c] = *(const bf16x8*)(p.B + bRow[c] + kc);
    }
  }

  for (int k0 = 0; k0 < p.K; k0 += 64) {
    __syncthreads();
    #pragma unroll
    for (int c = 0; c < 4; ++c) {
      *(bf16x8*)&As[wIdx[c]] = ra[c];
      *(bf16x8*)&Bs[wIdx[c]] = rb[c];
    }
    __syncthreads();
    if (k0 + 64 < p.K) {
      long kc = (long)(k0 + 64 + pcol * 8);
      long ka = (kc >> 6) * p.sAh + (kc & 63);
      #pragma unroll
      for (int c = 0; c < 4; ++c) {
        ra[c] = *(const bf16x8*)(p.A + aRow[c] + ka);
        rb[c] = *(const bf16x8*)(p.B + bRow[c] + kc);
      }
    }
    #pragma unroll
    for (int kk = 0; kk < 2; ++kk) {
      bf16x8 af[4], bf[4];
      #pragma unroll
      for (int f = 0; f < 4; ++f) {
        af[f] = *(const bf16x8*)&As[aOff[f][kk]];
        bf[f] = *(const bf16x8*)&Bs[bOff[f][kk]];
      }
      #pragma unroll
      for (int i = 0; i < 4; ++i)
        #pragma unroll
        for (int j = 0; j < 4; ++j)
          acc[i][j] = __builtin_amdgcn_mfma_f32_16x16x32_bf16(af[i], bf[j], acc[i][j], 0, 0, 0);
    }
  }

  // epilogue
  float bias4[4];
  long ncol[4];
  #pragma unroll
  for (int j = 0; j < 4; ++j) {
    long n = bn + wc * 64 + j * 16 + rA;
    ncol[j] = (n >> 6) * p.sCh + (n & 63);
    bias4[j] = p.hasbias ? p.bias[n] : 0.f;
  }
  #pragma unroll
  for (int i = 0; i < 4; ++i) {
    #pragma unroll
    for (int r = 0; r < 4; ++r) {
      long m = bm + wr * 64 + i * 16 + g * 4 + r;
      long mb = (m >> 11) * p.sCb + (m & 2047) * p.sCt;
      #pragma unroll
      for (int j = 0; j < 4; ++j) {
        long ca = mb + ncol[j];
        float v = p.alpha * acc[i][j][r] + bias4[j];
        if (p.relu) v = fmaxf(v, 0.f);
        if (p.hasres) v += p.res[ca];
        if (p.cbf16) ((short*)p.C)[ca] = f2bf(v);
        else ((float*)p.C)[ca] = v;
      }
    }
  }
}

// ============================ MFMA flash attention (bf16 in/out) ============================
// Q,K,V,att: [B,H,T,DH] bf16. Block: 256 thr (4 waves), 64 q-rows (16 per wave), KV tile 64.
// Swapped QK^T (A=K, B=Q^T) -> S^T; per-q softmax = 2 shuffles; P via wave-private
// swizzled LDS; PV with A=P, B=V (scalar V-frag reads, conflict-free).
__global__ __launch_bounds__(256) void attn_mfma_kernel(const short* __restrict__ q,
    const short* __restrict__ k, const short* __restrict__ v, short* __restrict__ att) {
  __shared__ short Ks[64 * 64];           // swizzled: chunk ^= s&7
  __shared__ short Vs[64 * 64];           // linear [s][d]
  __shared__ short Pq[4 * 16 * 64];       // per-wave [16 q][64 s], swizzled (q&7)<<3

  const int t = threadIdx.x;
  const int lane = t & 63, wid = t >> 6;
  const int bh = blockIdx.x >> 5;
  const int q0blk = (blockIdx.x & 31) * 64;
  const int rA = lane & 15;               // q within 16 (as input col / A-row)
  const int g  = lane >> 4;
  const int xq = (rA & 7) << 3;

  const short* Qg = q + (size_t)bh * T_SEQ * DHEAD;
  const short* Kg = k + (size_t)bh * T_SEQ * DHEAD;
  const short* Vg = v + (size_t)bh * T_SEQ * DHEAD;

  // Q fragments (B-operand): lane holds Q[q0w + rA][g*8 .. +8] for each 32-d half
  const int q0w = q0blk + wid * 16;
  bf16x8 qf0 = *(const bf16x8*)(Qg + (size_t)(q0w + rA) * DHEAD + g * 8);
  bf16x8 qf1 = *(const bf16x8*)(Qg + (size_t)(q0w + rA) * DHEAD + 32 + g * 8);

  // staging constants
  const int sp = t & 7;                   // chunk col
  short* Pw = Pq + wid * 1024;

  float mrun = -1e30f, lrun = 0.f;
  f32x4 acco[4] = {};

  bf16x8 kreg[2], vreg[2];
  #pragma unroll
  for (int c = 0; c < 2; ++c) {
    int idx = c * 256 + t;
    kreg[c] = *(const bf16x8*)(Kg + (size_t)(idx >> 3) * DHEAD + sp * 8);
    vreg[c] = *(const bf16x8*)(Vg + (size_t)(idx >> 3) * DHEAD + sp * 8);
  }

  for (int tile = 0; tile < T_SEQ / 64; ++tile) {
    __syncthreads();
    #pragma unroll
    for (int c = 0; c < 2; ++c) {
      int idx = c * 256 + t;
      int s = idx >> 3;
      *(bf16x8*)&Ks[s * 64 + ((sp ^ (s & 7)) << 3)] = kreg[c];
      *(bf16x8*)&Vs[idx * 8] = vreg[c];
    }
    __syncthreads();
    if (tile + 1 < T_SEQ / 64) {
      int s0n = (tile + 1) * 64;
      #pragma unroll
      for (int c = 0; c < 2; ++c) {
        int idx = c * 256 + t;
        kreg[c] = *(const bf16x8*)(Kg + (size_t)(s0n + (idx >> 3)) * DHEAD + sp * 8);
        vreg[c] = *(const bf16x8*)(Vg + (size_t)(s0n + (idx >> 3)) * DHEAD + sp * 8);
      }
    }

    // ---- QK^T: S^T[s][q], 4 subtiles of 16 s ----
    f32x4 accs[4];
    #pragma unroll
    for (int st = 0; st < 4; ++st) {
      int srow = st * 16 + rA;
      bf16x8 kf0 = *(const bf16x8*)&Ks[srow * 64 + ((g ^ (rA & 7)) << 3)];
      bf16x8 kf1 = *(const bf16x8*)&Ks[srow * 64 + (((g + 4) ^ (rA & 7)) << 3)];
      f32x4 z = {};
      z = __builtin_amdgcn_mfma_f32_16x16x32_bf16(kf0, qf0, z, 0, 0, 0);
      accs[st] = __builtin_amdgcn_mfma_f32_16x16x32_bf16(kf1, qf1, z, 0, 0, 0);
    }

    // ---- online softmax over this 64-s tile (per q = rA) ----
    float tm = -1e30f;
    #pragma unroll
    for (int st = 0; st < 4; ++st)
      #pragma unroll
      for (int r = 0; r < 4; ++r) tm = fmaxf(tm, accs[st][r]);
    tm = fmaxf(tm, __shfl_xor(tm, 16));
    tm = fmaxf(tm, __shfl_xor(tm, 32));
    float mnew = fmaxf(mrun, tm);
    float ts = 0.f;
    float pv[16];
    #pragma unroll
    for (int st = 0; st < 4; ++st)
      #pragma unroll
      for (int r = 0; r < 4; ++r) {
        float e = __expf(accs[st][r] - mnew);
        pv[st * 4 + r] = e;
        ts += e;
      }
    ts += __shfl_xor(ts, 16);
    ts += __shfl_xor(ts, 32);
    float corr = __expf(mrun - mnew);
    lrun = lrun * corr + ts;
    mrun = mnew;

    // ---- write P^T values (q=rA, s=st*16+g*4+r) into wave-private swizzled Pq[q][s] ----
    #pragma unroll
    for (int st = 0; st < 4; ++st) {
      short4v pk;
      pk.x = f2bf(pv[st * 4 + 0]);
      pk.y = f2bf(pv[st * 4 + 1]);
      pk.z = f2bf(pv[st * 4 + 2]);
      pk.w = f2bf(pv[st * 4 + 3]);
      *(short4v*)&Pw[(rA * 64 + st * 16 + g * 4) ^ xq] = pk;
    }
    asm volatile("s_waitcnt lgkmcnt(0)" ::: "memory");

    // ---- rescale O, then PV ----
    float c4r[4];
    #pragma unroll
    for (int r = 0; r < 4; ++r) c4r[r] = __shfl(corr, g * 4 + r);
    #pragma unroll
    for (int dt = 0; dt < 4; ++dt)
      #pragma unroll
      for (int r = 0; r < 4; ++r) acco[dt][r] *= c4r[r];

    #pragma unroll
    for (int sk = 0; sk < 2; ++sk) {
      bf16x8 pf = *(const bf16x8*)&Pw[(rA * 64 + sk * 32 + g * 8) ^ xq];
      #pragma unroll
      for (int dt = 0; dt < 4; ++dt) {
        bf16x8 vf;
        #pragma unroll
        for (int j = 0; j < 8; ++j)
          vf[j] = Vs[(sk * 32 + g * 8 + j) * 64 + dt * 16 + rA];
        acco[dt] = __builtin_amdgcn_mfma_f32_16x16x32_bf16(pf, vf, acco[dt], 0, 0, 0);
      }
    }
  }

  // ---- finalize: divide by l, store O[q][d] (row = g*4+r, col = dt*16+rA) ----
  float l4[4];
  #pragma unroll
  for (int r = 0; r < 4; ++r) l4[r] = 1.0f / __shfl(lrun, g * 4 + r);
  #pragma unroll
  for (int dt = 0; dt < 4; ++dt)
    #pragma unroll
    for (int r = 0; r < 4; ++r)
      att[(size_t)bh * T_SEQ * DHEAD + (size_t)(q0w + g * 4 + r) * DHEAD + dt * 16 + rA] =
          f2bf(acco[dt][r] * l4[r]);
}

// ============================ head: bf16 h [8192,1024] @ Wu[1024,2] + bu ============================
__global__ __launch_bounds__(256) void head_kernel(const short* __restrict__ h,
    const float* __restrict__ Wu, const float* __restrict__ bu, float* __restrict__ out) {
  __shared__ float sm[8];
  int row = blockIdx.x;
  const short* hr = h + (size_t)row * E_DIM;
  float a0 = 0.f, a1 = 0.f;
  for (int i = threadIdx.x; i < E_DIM; i += 256) {
    float hv = bf2f(hr[i]);
    a0 = fmaf(hv, Wu[i * 2 + 0], a0);
    a1 = fmaf(hv, Wu[i * 2 + 1], a1);
  }
  #pragma unroll
  for (int off = 32; off; off >>= 1) {
    a0 += __shfl_xor(a0, off, 64);
    a1 += __shfl_xor(a1, off, 64);
  }
  int lane = threadIdx.x & 63, wid = threadIdx.x >> 6;
  if (lane == 0) { sm[wid] = a0; sm[4 + wid] = a1; }
  __syncthreads();
  if (threadIdx.x == 0) {
    out[row * 2 + 0] = sm[0] + sm[1] + sm[2] + sm[3] + bu[0];
    out[row * 2 + 1] = sm[4] + sm[5] + sm[6] + sm[7] + bu[1];
  }
}

// ============================ launcher ============================
static inline void launch_gemm(hipStream_t stream, int N,
    const short* A, long sAb, long sAt, long sAh,
    const short* B, long sBh, long sBd,
    void* C, long sCb, long sCt, long sCh,
    const float* bias, const float* res, int K, float alpha,
    int relu, int cbf16) {
  GemmP p;
  p.A = A; p.B = B; p.C = C; p.bias = bias; p.res = res;
  p.sAb = sAb; p.sAt = sAt; p.sAh = sAh;
  p.sBh = sBh; p.sBd = sBd;
  p.sCb = sCb; p.sCt = sCt; p.sCh = sCh;
  p.K = K; p.alpha = alpha; p.relu = relu; p.cbf16 = cbf16;
  p.hasbias = bias != nullptr; p.hasres = res != nullptr;
  dim3 grid(N / 128, (NB * T_SEQ) / 128);
  gemm_bf16<<<grid, 256, 0, stream>>>(p);
}

extern "C" void kernel_launch(void* const* d_in, const int* in_sizes, int n_in,
                              void* d_out, int out_size, void* d_ws, size_t ws_size,
                              hipStream_t stream) {
  const int*   tokens = (const int*)d_in[0];
  const float* emb_w  = (const float*)d_in[1];
  const float* pos_w  = (const float*)d_in[2];
  const float* Wq     = (const float*)d_in[3];
  const float* Wk     = (const float*)d_in[4];
  const float* Wv     = (const float*)d_in[5];
  const float* Wo     = (const float*)d_in[6];
  const float* ln1_g  = (const float*)d_in[7];
  const float* ln1_b  = (const float*)d_in[8];
  const float* W1     = (const float*)d_in[9];
  const float* b1     = (const float*)d_in[10];
  const float* W2     = (const float*)d_in[11];
  const float* b2     = (const float*)d_in[12];
  const float* ln2_g  = (const float*)d_in[13];
  const float* ln2_b  = (const float*)d_in[14];
  const float* lnf_g  = (const float*)d_in[15];
  const float* lnf_b  = (const float*)d_in[16];
  const float* Wu     = (const float*)d_in[17];
  const float* bu     = (const float*)d_in[18];
  float* out = (float*)d_out;

  // ---- workspace layout (bytes) ----
  char* ws = (char*)d_ws;
  float* X    = (float*)(ws);                        // 33,554,432 B  f32 [B,T,E]
  short* Hb   = (short*)(ws + 33554432);             // 16,777,216 B  bf16 (LN out / attn out)
  short* Qb   = (short*)(ws + 50331648);             // 16 MB bf16 [B,H,T,DH]
  short* Kb   = (short*)(ws + 67108864);
  short* Vb   = (short*)(ws + 83886080);
  short* FFH  = (short*)(ws + 100663296);            // 67,108,864 B bf16 [8192,4096]
  short* WqT  = (short*)(ws + 167772160);            // 2 MB [16][64][1024]
  short* WkT  = (short*)(ws + 169869312);
  short* WvT  = (short*)(ws + 171966464);
  short* WoT  = (short*)(ws + 174063616);            // 2 MB [1024][1024]
  short* W1T  = (short*)(ws + 176160768);            // 8 MB [4096][1024]
  short* W2T  = (short*)(ws + 184549376);            // 8 MB [1024][4096]

  const float scale = 0.022097086912079608f;         // 1/sqrt(2048)

  embed_kernel<<<32768, 256, 0, stream>>>(tokens, emb_w, pos_w, X);

  dim3 tb(32, 8);
  for (int l = 0; l < NLAYER; ++l) {
    // per-layer weight cast+transpose to B^T bf16
    castT_kernel<<<dim3(32, 2, 16), tb, 0, stream>>>(Wq + (size_t)l * 1048576, WqT, 1024, 64);
    castT_kernel<<<dim3(32, 2, 16), tb, 0, stream>>>(Wk + (size_t)l * 1048576, WkT, 1024, 64);
    castT_kernel<<<dim3(32, 2, 16), tb, 0, stream>>>(Wv + (size_t)l * 1048576, WvT, 1024, 64);
    castT_kernel<<<dim3(32, 32, 1), tb, 0, stream>>>(Wo + (size_t)l * 1048576, WoT, 1024, 1024);
    castT_kernel<<<dim3(32, 128, 1), tb, 0, stream>>>(W1 + (size_t)l * 4194304, W1T, 1024, 4096);
    castT_kernel<<<dim3(128, 32, 1), tb, 0, stream>>>(W2 + (size_t)l * 4194304, W2T, 4096, 1024);

    ln_bf16_kernel<<<8192, 256, 0, stream>>>(X, ln1_g + l * 1024, ln1_b + l * 1024, Hb);

    // QKV projections: A=Hb [8192,1024], B^T=[H][DH][E], C=[B,H,T,DH] bf16
    launch_gemm(stream, 1024, Hb, 2097152, 1024, 64, WqT, 65536, 1024,
                Qb, 2097152, 64, 131072, nullptr, nullptr, 1024, scale, 0, 1);
    launch_gemm(stream, 1024, Hb, 2097152, 1024, 64, WkT, 65536, 1024,
                Kb, 2097152, 64, 131072, nullptr, nullptr, 1024, 1.0f, 0, 1);
    launch_gemm(stream, 1024, Hb, 2097152, 1024, 64, WvT, 65536, 1024,
                Vb, 2097152, 64, 131072, nullptr, nullptr, 1024, 1.0f, 0, 1);

    attn_mfma_kernel<<<2048, 256, 0, stream>>>(Qb, Kb, Vb, Hb);   // att -> Hb

    // Wo: A=att [B,H,T,DH], C=X f32 (+res X)
    launch_gemm(stream, 1024, Hb, 2097152, 64, 131072, WoT, 65536, 1024,
                X, 2097152, 1024, 64, nullptr, X, 1024, 1.0f, 0, 0);

    ln_bf16_kernel<<<8192, 256, 0, stream>>>(X, ln2_g + l * 1024, ln2_b + l * 1024, Hb);

    // W1: relu(h@W1+b1) -> FFH bf16
    launch_gemm(stream, 4096, Hb, 2097152, 1024, 64, W1T, 65536, 1024,
                FFH, 8388608, 4096, 64, b1 + (size_t)l * 4096, nullptr, 1024, 1.0f, 1, 1);
    // W2: X += FFH@W2 + b2
    launch_gemm(stream, 1024, FFH, 8388608, 4096, 64, W2T, 262144, 4096,
                X, 2097152, 1024, 64, b2 + (size_t)l * 1024, X, 4096, 1.0f, 0, 0);
  }

  ln_bf16_kernel<<<8192, 256, 0, stream>>>(X, lnf_g, lnf_b, Hb);
  head_kernel<<<8192, 256, 0, stream>>>(Hb, Wu, bu, out);
}

// Round 4
// 3651.310 us; speedup vs baseline: 23.5290x; 1.1980x over previous
//
#include <hip/hip_runtime.h>
#include <hip/hip_bf16.h>
#include <math.h>

#define E_DIM 1024
#define T_SEQ 2048
#define NH 16
#define DHEAD 64
#define NB 4
#define NLAYER 8

typedef __attribute__((ext_vector_type(8))) short bf16x8;
typedef __attribute__((ext_vector_type(4))) short short4v;
typedef __attribute__((ext_vector_type(4))) float f32x4;

static __device__ __forceinline__ short f2bf(float f) {
  union { __hip_bfloat16 h; short s; } u;
  u.h = __float2bfloat16(f);
  return u.s;
}
static __device__ __forceinline__ float bf2f(short s) {
  union { unsigned u; float f; } v;
  v.u = ((unsigned)(unsigned short)s) << 16;
  return v.f;
}

// ============================ embedding (f32) ============================
__global__ __launch_bounds__(256) void embed_kernel(const int* __restrict__ tokens,
    const float* __restrict__ emb, const float* __restrict__ pos, float* __restrict__ x) {
  int idx = blockIdx.x * 256 + threadIdx.x;
  int bt = idx >> 10;
  int e  = idx & 1023;
  int t  = bt & (T_SEQ - 1);
  int tok = tokens[bt];
  x[idx] = emb[tok * E_DIM + e] + pos[t * E_DIM + e];
}

// ============================ layernorm f32 -> bf16 ============================
__global__ __launch_bounds__(256) void ln_bf16_kernel(const float* __restrict__ x,
    const float* __restrict__ g, const float* __restrict__ b, short* __restrict__ out) {
  __shared__ float s1[4], s2[4];
  int row = blockIdx.x;
  const float4* xr = (const float4*)(x + (size_t)row * E_DIM);
  float4 xv = xr[threadIdx.x];
  float s = xv.x + xv.y + xv.z + xv.w;
  float q = xv.x*xv.x + xv.y*xv.y + xv.z*xv.z + xv.w*xv.w;
  #pragma unroll
  for (int off = 32; off; off >>= 1) {
    s += __shfl_xor(s, off, 64);
    q += __shfl_xor(q, off, 64);
  }
  int lane = threadIdx.x & 63, wid = threadIdx.x >> 6;
  if (lane == 0) { s1[wid] = s; s2[wid] = q; }
  __syncthreads();
  float mean = (s1[0] + s1[1] + s1[2] + s1[3]) * (1.0f / E_DIM);
  float ms   = (s2[0] + s2[1] + s2[2] + s2[3]) * (1.0f / E_DIM);
  float rstd = rsqrtf(ms - mean * mean + 1e-5f);
  float4 gv = ((const float4*)g)[threadIdx.x];
  float4 bv = ((const float4*)b)[threadIdx.x];
  short4v ov;
  ov.x = f2bf((xv.x - mean) * rstd * gv.x + bv.x);
  ov.y = f2bf((xv.y - mean) * rstd * gv.y + bv.y);
  ov.z = f2bf((xv.z - mean) * rstd * gv.z + bv.z);
  ov.w = f2bf((xv.w - mean) * rstd * gv.w + bv.w);
  *(short4v*)(out + (size_t)row * E_DIM + threadIdx.x * 4) = ov;
}

// ============================ cast+transpose f32[K][N] -> bf16[N][K] ============================
// grid: (K/32, N/32, BATCH), block (32,8)
__global__ void castT_kernel(const float* __restrict__ in, short* __restrict__ out,
                             int K, int N) {
  __shared__ float tile[32][33];
  int k0 = blockIdx.x * 32, n0 = blockIdx.y * 32;
  const float* ib = in + (size_t)blockIdx.z * K * N;
  short* ob = out + (size_t)blockIdx.z * N * K;
  int tx = threadIdx.x, ty = threadIdx.y;
  #pragma unroll
  for (int i = 0; i < 4; ++i)
    tile[ty + 8 * i][tx] = ib[(size_t)(k0 + ty + 8 * i) * N + n0 + tx];
  __syncthreads();
  #pragma unroll
  for (int i = 0; i < 4; ++i)
    ob[(size_t)(n0 + ty + 8 * i) * K + k0 + tx] = f2bf(tile[tx][ty + 8 * i]);
}

// ============================ bf16 MFMA GEMM ============================
// C[m,n] = alpha * sum_k A[m,k] * BT[n,k]  (+bias) (relu) (+res), strided addressing.
// 128x128 tile, BK=64, 4 waves each own a 64x64 quadrant (4x4 frags of 16x16).
struct GemmP {
  const short* A; const short* B; void* C;
  const float* bias; const float* res;
  long sAb, sAt, sAh;       // m>>11, m&2047, k>>6 (k&63 stride 1)
  long sBh, sBd;            // n>>6, n&63 (k stride 1)
  long sCb, sCt, sCh;       // m>>11, m&2047, n>>6 (n&63 stride 1)
  int K; float alpha; int relu; int cbf16; int hasbias; int hasres;
};

__global__ __launch_bounds__(256) void gemm_bf16(GemmP p) {
  __shared__ __align__(16) short As[128 * 64];
  __shared__ __align__(16) short Bs[128 * 64];
  const int t = threadIdx.x;
  const int lane = t & 63, wid = t >> 6;
  const int wr = wid >> 1, wc = wid & 1;
  const long bm = (long)blockIdx.y * 128, bn = (long)blockIdx.x * 128;

  const int prow = t >> 3;
  const int pcol = t & 7;
  long aRow[4], bRow[4];
  int wIdx[4];
  #pragma unroll
  for (int c = 0; c < 4; ++c) {
    int r = c * 32 + prow;
    long gm = bm + r, gn = bn + r;
    aRow[c] = (gm >> 11) * p.sAb + (gm & 2047) * p.sAt;
    bRow[c] = (gn >> 6) * p.sBh + (gn & 63) * p.sBd;
    wIdx[c] = r * 64 + ((pcol ^ (r & 7)) << 3);
  }

  const int rA = lane & 15;
  const int g  = lane >> 4;
  int aOff[4][2], bOff[4][2];
  #pragma unroll
  for (int f = 0; f < 4; ++f) {
    int rowa = wr * 64 + f * 16 + rA;
    int rowb = wc * 64 + f * 16 + rA;
    #pragma unroll
    for (int kk = 0; kk < 2; ++kk) {
      aOff[f][kk] = rowa * 64 + (((g + kk * 4) ^ (rowa & 7)) << 3);
      bOff[f][kk] = rowb * 64 + (((g + kk * 4) ^ (rowb & 7)) << 3);
    }
  }

  f32x4 acc[4][4] = {};
  bf16x8 ra[4], rb[4];
  {
    long kc = (long)(pcol * 8);
    long ka = (kc >> 6) * p.sAh + (kc & 63);
    #pragma unroll
    for (int c = 0; c < 4; ++c) {
      ra[c] = *(const bf16x8*)(p.A + aRow[c] + ka);
      rb[c] = *(const bf16x8*)(p.B + bRow[c] + kc);
    }
  }

  for (int k0 = 0; k0 < p.K; k0 += 64) {
    __syncthreads();
    #pragma unroll
    for (int c = 0; c < 4; ++c) {
      *(bf16x8*)&As[wIdx[c]] = ra[c];
      *(bf16x8*)&Bs[wIdx[c]] = rb[c];
    }
    __syncthreads();
    if (k0 + 64 < p.K) {
      long kc = (long)(k0 + 64 + pcol * 8);
      long ka = (kc >> 6) * p.sAh + (kc & 63);
      #pragma unroll
      for (int c = 0; c < 4; ++c) {
        ra[c] = *(const bf16x8*)(p.A + aRow[c] + ka);
        rb[c] = *(const bf16x8*)(p.B + bRow[c] + kc);
      }
    }
    #pragma unroll
    for (int kk = 0; kk < 2; ++kk) {
      bf16x8 af[4], bf[4];
      #pragma unroll
      for (int f = 0; f < 4; ++f) {
        af[f] = *(const bf16x8*)&As[aOff[f][kk]];
        bf[f] = *(const bf16x8*)&Bs[bOff[f][kk]];
      }
      #pragma unroll
      for (int i = 0; i < 4; ++i)
        #pragma unroll
        for (int j = 0; j < 4; ++j)
          acc[i][j] = __builtin_amdgcn_mfma_f32_16x16x32_bf16(af[i], bf[j], acc[i][j], 0, 0, 0);
    }
  }

  float bias4[4];
  long ncol[4];
  #pragma unroll
  for (int j = 0; j < 4; ++j) {
    long n = bn + wc * 64 + j * 16 + rA;
    ncol[j] = (n >> 6) * p.sCh + (n & 63);
    bias4[j] = p.hasbias ? p.bias[n] : 0.f;
  }
  #pragma unroll
  for (int i = 0; i < 4; ++i) {
    #pragma unroll
    for (int r = 0; r < 4; ++r) {
      long m = bm + wr * 64 + i * 16 + g * 4 + r;
      long mb = (m >> 11) * p.sCb + (m & 2047) * p.sCt;
      #pragma unroll
      for (int j = 0; j < 4; ++j) {
        long ca = mb + ncol[j];
        float v = p.alpha * acc[i][j][r] + bias4[j];
        if (p.relu) v = fmaxf(v, 0.f);
        if (p.hasres) v += p.res[ca];
        if (p.cbf16) ((short*)p.C)[ca] = f2bf(v);
        else ((float*)p.C)[ca] = v;
      }
    }
  }
}

// ============================ MFMA flash attention v2 ============================
// QKV packed [B][3][H][T][DH] bf16; att out [B,H,T,DH] bf16.
// 512 thr (8 waves), 128 q-rows/block (16/wave), KV tile 64.
// K tile: XOR-swizzled rows. V tile: skewed-transposed Vt[d][f(s,d)] so PV
// B-fragments are contiguous b128 reads; scalar writes land 2-way max.
__global__ __launch_bounds__(512) void attn_mfma_kernel(const short* __restrict__ qkv,
                                                        short* __restrict__ att) {
  __shared__ __align__(16) short Ks[64 * 64];
  __shared__ __align__(16) short Vt[64 * 64];
  __shared__ __align__(16) short Pq[8 * 16 * 64];

  const int t = threadIdx.x;
  const int lane = t & 63, wid = t >> 6;
  const int bh = blockIdx.x >> 4;           // 64 (b,h) groups, 16 q-blocks each
  const int b = bh >> 4, h = bh & 15;
  const int q0blk = (blockIdx.x & 15) * 128;
  const int rA = lane & 15;
  const int g  = lane >> 4;
  const int xq = (rA & 7) << 3;
  const float scale = 0.022097086912079608f;   // 1/sqrt(2048)

  const short* Qg = qkv + (size_t)b * 6291456 + (size_t)h * 131072;
  const short* Kg = Qg + 2097152;
  const short* Vg = Qg + 4194304;

  const int q0w = q0blk + wid * 16;
  bf16x8 qf0 = *(const bf16x8*)(Qg + (size_t)(q0w + rA) * DHEAD + g * 8);
  bf16x8 qf1 = *(const bf16x8*)(Qg + (size_t)(q0w + rA) * DHEAD + 32 + g * 8);

  short* Pw = Pq + wid * 1024;
  const int ss = t >> 3, sp = t & 7;        // staging: row s, chunk sp

  float mrun = -1e30f, lrun = 0.f;
  f32x4 acco[4] = {};

  bf16x8 kreg = *(const bf16x8*)(Kg + (size_t)ss * DHEAD + sp * 8);
  bf16x8 vreg = *(const bf16x8*)(Vg + (size_t)ss * DHEAD + sp * 8);

  for (int tile = 0; tile < T_SEQ / 64; ++tile) {
    __syncthreads();
    *(bf16x8*)&Ks[ss * 64 + ((sp ^ (ss & 7)) << 3)] = kreg;
    #pragma unroll
    for (int j = 0; j < 8; ++j) {           // skewed V^T scalar writes (2-way max)
      int d = sp * 8 + j;
      Vt[d * 64 + ((ss + 8 * (sp + j)) & 63)] = vreg[j];
    }
    __syncthreads();
    if (tile + 1 < T_SEQ / 64) {
      kreg = *(const bf16x8*)(Kg + (size_t)((tile + 1) * 64 + ss) * DHEAD + sp * 8);
      vreg = *(const bf16x8*)(Vg + (size_t)((tile + 1) * 64 + ss) * DHEAD + sp * 8);
    }

    // ---- QK^T: S^T[s][q] ----
    f32x4 accs[4];
    __builtin_amdgcn_s_setprio(1);
    #pragma unroll
    for (int st = 0; st < 4; ++st) {
      int srow = st * 16 + rA;
      bf16x8 kf0 = *(const bf16x8*)&Ks[srow * 64 + ((g ^ (rA & 7)) << 3)];
      bf16x8 kf1 = *(const bf16x8*)&Ks[srow * 64 + (((g + 4) ^ (rA & 7)) << 3)];
      f32x4 z = {};
      z = __builtin_amdgcn_mfma_f32_16x16x32_bf16(kf0, qf0, z, 0, 0, 0);
      accs[st] = __builtin_amdgcn_mfma_f32_16x16x32_bf16(kf1, qf1, z, 0, 0, 0);
    }
    __builtin_amdgcn_s_setprio(0);

    // ---- scale + online softmax (per q = rA) ----
    float tm = -1e30f;
    #pragma unroll
    for (int st = 0; st < 4; ++st) {
      #pragma unroll
      for (int r = 0; r < 4; ++r) {
        accs[st][r] *= scale;
        tm = fmaxf(tm, accs[st][r]);
      }
    }
    tm = fmaxf(tm, __shfl_xor(tm, 16));
    tm = fmaxf(tm, __shfl_xor(tm, 32));
    float mnew = fmaxf(mrun, tm);
    float ts = 0.f;
    float pv[16];
    #pragma unroll
    for (int st = 0; st < 4; ++st)
      #pragma unroll
      for (int r = 0; r < 4; ++r) {
        float e = __expf(accs[st][r] - mnew);
        pv[st * 4 + r] = e;
        ts += e;
      }
    ts += __shfl_xor(ts, 16);
    ts += __shfl_xor(ts, 32);
    float corr = __expf(mrun - mnew);
    lrun = lrun * corr + ts;
    mrun = mnew;

    // ---- P^T into wave-private swizzled Pq[q][s] ----
    #pragma unroll
    for (int st = 0; st < 4; ++st) {
      short4v pk;
      pk.x = f2bf(pv[st * 4 + 0]);
      pk.y = f2bf(pv[st * 4 + 1]);
      pk.z = f2bf(pv[st * 4 + 2]);
      pk.w = f2bf(pv[st * 4 + 3]);
      *(short4v*)&Pw[(rA * 64 + st * 16 + g * 4) ^ xq] = pk;
    }
    asm volatile("s_waitcnt lgkmcnt(0)" ::: "memory");

    // ---- rescale O, then PV ----
    float c4r[4];
    #pragma unroll
    for (int r = 0; r < 4; ++r) c4r[r] = __shfl(corr, g * 4 + r);
    #pragma unroll
    for (int dt = 0; dt < 4; ++dt)
      #pragma unroll
      for (int r = 0; r < 4; ++r) acco[dt][r] *= c4r[r];

    __builtin_amdgcn_s_setprio(1);
    #pragma unroll
    for (int sk = 0; sk < 2; ++sk) {
      bf16x8 pf = *(const bf16x8*)&Pw[(rA * 64 + sk * 32 + g * 8) ^ xq];
      #pragma unroll
      for (int dt = 0; dt < 4; ++dt) {
        int d = dt * 16 + rA;
        bf16x8 vf = *(const bf16x8*)&Vt[d * 64 +
            ((sk * 32 + g * 8 + 8 * (dt * 2 + (rA >> 3) + (rA & 7))) & 63)];
        acco[dt] = __builtin_amdgcn_mfma_f32_16x16x32_bf16(pf, vf, acco[dt], 0, 0, 0);
      }
    }
    __builtin_amdgcn_s_setprio(0);
  }

  float l4[4];
  #pragma unroll
  for (int r = 0; r < 4; ++r) l4[r] = 1.0f / __shfl(lrun, g * 4 + r);
  #pragma unroll
  for (int dt = 0; dt < 4; ++dt)
    #pragma unroll
    for (int r = 0; r < 4; ++r)
      att[(size_t)bh * T_SEQ * DHEAD + (size_t)(q0w + g * 4 + r) * DHEAD + dt * 16 + rA] =
          f2bf(acco[dt][r] * l4[r]);
}

// ============================ head ============================
__global__ __launch_bounds__(256) void head_kernel(const short* __restrict__ h,
    const float* __restrict__ Wu, const float* __restrict__ bu, float* __restrict__ out) {
  __shared__ float sm[8];
  int row = blockIdx.x;
  const short* hr = h + (size_t)row * E_DIM;
  float a0 = 0.f, a1 = 0.f;
  for (int i = threadIdx.x; i < E_DIM; i += 256) {
    float hv = bf2f(hr[i]);
    a0 = fmaf(hv, Wu[i * 2 + 0], a0);
    a1 = fmaf(hv, Wu[i * 2 + 1], a1);
  }
  #pragma unroll
  for (int off = 32; off; off >>= 1) {
    a0 += __shfl_xor(a0, off, 64);
    a1 += __shfl_xor(a1, off, 64);
  }
  int lane = threadIdx.x & 63, wid = threadIdx.x >> 6;
  if (lane == 0) { sm[wid] = a0; sm[4 + wid] = a1; }
  __syncthreads();
  if (threadIdx.x == 0) {
    out[row * 2 + 0] = sm[0] + sm[1] + sm[2] + sm[3] + bu[0];
    out[row * 2 + 1] = sm[4] + sm[5] + sm[6] + sm[7] + bu[1];
  }
}

// ============================ launcher ============================
static inline void launch_gemm(hipStream_t stream, int N,
    const short* A, long sAb, long sAt, long sAh,
    const short* B, long sBh, long sBd,
    void* C, long sCb, long sCt, long sCh,
    const float* bias, const float* res, int K, float alpha,
    int relu, int cbf16) {
  GemmP p;
  p.A = A; p.B = B; p.C = C; p.bias = bias; p.res = res;
  p.sAb = sAb; p.sAt = sAt; p.sAh = sAh;
  p.sBh = sBh; p.sBd = sBd;
  p.sCb = sCb; p.sCt = sCt; p.sCh = sCh;
  p.K = K; p.alpha = alpha; p.relu = relu; p.cbf16 = cbf16;
  p.hasbias = bias != nullptr; p.hasres = res != nullptr;
  dim3 grid(N / 128, (NB * T_SEQ) / 128);
  gemm_bf16<<<grid, 256, 0, stream>>>(p);
}

extern "C" void kernel_launch(void* const* d_in, const int* in_sizes, int n_in,
                              void* d_out, int out_size, void* d_ws, size_t ws_size,
                              hipStream_t stream) {
  const int*   tokens = (const int*)d_in[0];
  const float* emb_w  = (const float*)d_in[1];
  const float* pos_w  = (const float*)d_in[2];
  const float* Wq     = (const float*)d_in[3];
  const float* Wk     = (const float*)d_in[4];
  const float* Wv     = (const float*)d_in[5];
  const float* Wo     = (const float*)d_in[6];
  const float* ln1_g  = (const float*)d_in[7];
  const float* ln1_b  = (const float*)d_in[8];
  const float* W1     = (const float*)d_in[9];
  const float* b1     = (const float*)d_in[10];
  const float* W2     = (const float*)d_in[11];
  const float* b2     = (const float*)d_in[12];
  const float* ln2_g  = (const float*)d_in[13];
  const float* ln2_b  = (const float*)d_in[14];
  const float* lnf_g  = (const float*)d_in[15];
  const float* lnf_b  = (const float*)d_in[16];
  const float* Wu     = (const float*)d_in[17];
  const float* bu     = (const float*)d_in[18];
  float* out = (float*)d_out;

  // ---- workspace layout (bytes) ----
  char* ws = (char*)d_ws;
  float* X     = (float*)(ws);                       // 32 MB f32 [B,T,E]
  short* Hb    = (short*)(ws + 33554432);            // 16 MB bf16 (LN out / attn out)
  short* QKVb  = (short*)(ws + 50331648);            // 48 MB bf16 [B][3][H][T][DH]
  short* FFH   = (short*)(ws + 100663296);           // 64 MB bf16 [8192,4096]
  short* WqkvT = (short*)(ws + 167772160);           // 6 MB  [3][16][64][1024]
  short* WoT   = (short*)(ws + 174063616);           // 2 MB  [1024][1024]
  short* W1T   = (short*)(ws + 176160768);           // 8 MB  [4096][1024]
  short* W2T   = (short*)(ws + 184549376);           // 8 MB  [1024][4096]

  embed_kernel<<<32768, 256, 0, stream>>>(tokens, emb_w, pos_w, X);

  dim3 tb(32, 8);
  for (int l = 0; l < NLAYER; ++l) {
    castT_kernel<<<dim3(32, 2, 16), tb, 0, stream>>>(Wq + (size_t)l * 1048576, WqkvT, 1024, 64);
    castT_kernel<<<dim3(32, 2, 16), tb, 0, stream>>>(Wk + (size_t)l * 1048576, WqkvT + 1048576, 1024, 64);
    castT_kernel<<<dim3(32, 2, 16), tb, 0, stream>>>(Wv + (size_t)l * 1048576, WqkvT + 2097152, 1024, 64);
    castT_kernel<<<dim3(32, 32, 1), tb, 0, stream>>>(Wo + (size_t)l * 1048576, WoT, 1024, 1024);
    castT_kernel<<<dim3(32, 128, 1), tb, 0, stream>>>(W1 + (size_t)l * 4194304, W1T, 1024, 4096);
    castT_kernel<<<dim3(128, 32, 1), tb, 0, stream>>>(W2 + (size_t)l * 4194304, W2T, 4096, 1024);

    ln_bf16_kernel<<<8192, 256, 0, stream>>>(X, ln1_g + l * 1024, ln1_b + l * 1024, Hb);

    // merged QKV: N = 3072 (48 head-blocks), C -> [b][3][h][t][d]
    launch_gemm(stream, 3072, Hb, 2097152, 1024, 64, WqkvT, 65536, 1024,
                QKVb, 6291456, 64, 131072, nullptr, nullptr, 1024, 1.0f, 0, 1);

    attn_mfma_kernel<<<1024, 512, 0, stream>>>(QKVb, Hb);   // att -> Hb

    // Wo: A=att [B,H,T,DH], C=X f32 (+res X)
    launch_gemm(stream, 1024, Hb, 2097152, 64, 131072, WoT, 65536, 1024,
                X, 2097152, 1024, 64, nullptr, X, 1024, 1.0f, 0, 0);

    ln_bf16_kernel<<<8192, 256, 0, stream>>>(X, ln2_g + l * 1024, ln2_b + l * 1024, Hb);

    launch_gemm(stream, 4096, Hb, 2097152, 1024, 64, W1T, 65536, 1024,
                FFH, 8388608, 4096, 64, b1 + (size_t)l * 4096, nullptr, 1024, 1.0f, 1, 1);
    launch_gemm(stream, 1024, FFH, 8388608, 4096, 64, W2T, 262144, 4096,
                X, 2097152, 1024, 64, b2 + (size_t)l * 1024, X, 4096, 1.0f, 0, 0);
  }

  ln_bf16_kernel<<<8192, 256, 0, stream>>>(X, lnf_g, lnf_b, Hb);
  head_kernel<<<8192, 256, 0, stream>>>(Hb, Wu, bu, out);
}

// Round 5
// 3442.492 us; speedup vs baseline: 24.9562x; 1.0607x over previous
//
#include <hip/hip_runtime.h>
#include <hip/hip_bf16.h>
#include <math.h>

#define E_DIM 1024
#define T_SEQ 2048
#define NH 16
#define DHEAD 64
#define NB 4
#define NLAYER 8

typedef __attribute__((ext_vector_type(8))) short bf16x8;
typedef __attribute__((ext_vector_type(4))) short short4v;
typedef __attribute__((ext_vector_type(4))) float f32x4;

#if __has_builtin(__builtin_amdgcn_exp2f)
#define EXP2(x) __builtin_amdgcn_exp2f(x)
#else
#define EXP2(x) exp2f(x)
#endif

static __device__ __forceinline__ short f2bf(float f) {
  union { __hip_bfloat16 h; short s; } u;
  u.h = __float2bfloat16(f);
  return u.s;
}
static __device__ __forceinline__ float bf2f(short s) {
  union { unsigned u; float f; } v;
  v.u = ((unsigned)(unsigned short)s) << 16;
  return v.f;
}

// XCD-aware bijective block swizzle (valid when nwg % 8 == 0): consecutive
// resident-on-one-XCD blocks (orig%8) cover a contiguous chunk of tile space.
static __device__ __forceinline__ int xcd_swz(int orig, int nwg) {
  return (orig & 7) * (nwg >> 3) + (orig >> 3);
}

// ============================ embedding (f32) ============================
__global__ __launch_bounds__(256) void embed_kernel(const int* __restrict__ tokens,
    const float* __restrict__ emb, const float* __restrict__ pos, float* __restrict__ x) {
  int idx = blockIdx.x * 256 + threadIdx.x;
  int bt = idx >> 10;
  int e  = idx & 1023;
  int t  = bt & (T_SEQ - 1);
  int tok = tokens[bt];
  x[idx] = emb[tok * E_DIM + e] + pos[t * E_DIM + e];
}

// ============================ layernorm f32 -> bf16 ============================
__global__ __launch_bounds__(256) void ln_bf16_kernel(const float* __restrict__ x,
    const float* __restrict__ g, const float* __restrict__ b, short* __restrict__ out) {
  __shared__ float s1[4], s2[4];
  int row = blockIdx.x;
  const float4* xr = (const float4*)(x + (size_t)row * E_DIM);
  float4 xv = xr[threadIdx.x];
  float s = xv.x + xv.y + xv.z + xv.w;
  float q = xv.x*xv.x + xv.y*xv.y + xv.z*xv.z + xv.w*xv.w;
  #pragma unroll
  for (int off = 32; off; off >>= 1) {
    s += __shfl_xor(s, off, 64);
    q += __shfl_xor(q, off, 64);
  }
  int lane = threadIdx.x & 63, wid = threadIdx.x >> 6;
  if (lane == 0) { s1[wid] = s; s2[wid] = q; }
  __syncthreads();
  float mean = (s1[0] + s1[1] + s1[2] + s1[3]) * (1.0f / E_DIM);
  float ms   = (s2[0] + s2[1] + s2[2] + s2[3]) * (1.0f / E_DIM);
  float rstd = rsqrtf(ms - mean * mean + 1e-5f);
  float4 gv = ((const float4*)g)[threadIdx.x];
  float4 bv = ((const float4*)b)[threadIdx.x];
  short4v ov;
  ov.x = f2bf((xv.x - mean) * rstd * gv.x + bv.x);
  ov.y = f2bf((xv.y - mean) * rstd * gv.y + bv.y);
  ov.z = f2bf((xv.z - mean) * rstd * gv.z + bv.z);
  ov.w = f2bf((xv.w - mean) * rstd * gv.w + bv.w);
  *(short4v*)(out + (size_t)row * E_DIM + threadIdx.x * 4) = ov;
}

// ============================ merged per-layer weight prep ============================
// One launch transposes+casts all six weights: f32[K][N] -> bf16[N][K].
// Segments (blocks of 32x32 tiles): Wq/Wk/Wv 1024 ea, Wo 1024, W1 4096, W2 4096.
struct PrepP {
  const float *s0, *s1, *s2, *s3, *s4, *s5;
  short *d0, *d1, *d2, *d3, *d4, *d5;
};

__global__ void prep_kernel(PrepP p) {
  __shared__ float tile[32][33];
  int bid = blockIdx.x;
  const float* src; short* dst; int K, N, kb, local;
  if (bid < 1024)      { src = p.s0; dst = p.d0; K = 1024; N = 64;   kb = 32;  local = bid; }
  else if (bid < 2048) { src = p.s1; dst = p.d1; K = 1024; N = 64;   kb = 32;  local = bid - 1024; }
  else if (bid < 3072) { src = p.s2; dst = p.d2; K = 1024; N = 64;   kb = 32;  local = bid - 2048; }
  else if (bid < 4096) { src = p.s3; dst = p.d3; K = 1024; N = 1024; kb = 32;  local = bid - 3072; }
  else if (bid < 8192) { src = p.s4; dst = p.d4; K = 1024; N = 4096; kb = 32;  local = bid - 4096; }
  else                 { src = p.s5; dst = p.d5; K = 4096; N = 1024; kb = 128; local = bid - 8192; }
  int per = kb * (N >> 5);
  int z = local / per, rem = local % per;
  int k0 = (rem % kb) * 32, n0 = (rem / kb) * 32;
  src += (size_t)z * K * N;
  dst += (size_t)z * N * K;
  int tx = threadIdx.x, ty = threadIdx.y;
  #pragma unroll
  for (int i = 0; i < 4; ++i)
    tile[ty + 8 * i][tx] = src[(size_t)(k0 + ty + 8 * i) * N + n0 + tx];
  __syncthreads();
  #pragma unroll
  for (int i = 0; i < 4; ++i)
    dst[(size_t)(n0 + ty + 8 * i) * K + k0 + tx] = f2bf(tile[tx][ty + 8 * i]);
}

// ============================ bf16 MFMA GEMM ============================
// C[m,n] = a(n) * sum_k A[m,k] * BT[n,k]  (+bias) (relu) (+res); a(n)=alpha if n<alphaN.
// 128x128 tile, BK=64, 4 waves each own a 64x64 quadrant (4x4 frags of 16x16).
struct GemmP {
  const short* A; const short* B; void* C;
  const float* bias; const float* res;
  long sAb, sAt, sAh;       // m>>11, m&2047, k>>6 (k&63 stride 1)
  long sBh, sBd;            // n>>6, n&63 (k stride 1)
  long sCb, sCt, sCh;       // m>>11, m&2047, n>>6 (n&63 stride 1)
  int K; float alpha; int alphaN; int gridx;
  int relu; int cbf16; int hasbias; int hasres;
};

__global__ __launch_bounds__(256) void gemm_bf16(GemmP p) {
  __shared__ __align__(16) short As[128 * 64];
  __shared__ __align__(16) short Bs[128 * 64];
  const int t = threadIdx.x;
  const int lane = t & 63, wid = t >> 6;
  const int wr = wid >> 1, wc = wid & 1;
  const int wg = xcd_swz(blockIdx.x, gridDim.x);
  const long bm = (long)(wg / p.gridx) * 128, bn = (long)(wg % p.gridx) * 128;

  const int prow = t >> 3;
  const int pcol = t & 7;
  long aRow[4], bRow[4];
  int wIdx[4];
  #pragma unroll
  for (int c = 0; c < 4; ++c) {
    int r = c * 32 + prow;
    long gm = bm + r, gn = bn + r;
    aRow[c] = (gm >> 11) * p.sAb + (gm & 2047) * p.sAt;
    bRow[c] = (gn >> 6) * p.sBh + (gn & 63) * p.sBd;
    wIdx[c] = r * 64 + ((pcol ^ (r & 7)) << 3);
  }

  const int rA = lane & 15;
  const int g  = lane >> 4;
  int aOff[4][2], bOff[4][2];
  #pragma unroll
  for (int f = 0; f < 4; ++f) {
    int rowa = wr * 64 + f * 16 + rA;
    int rowb = wc * 64 + f * 16 + rA;
    #pragma unroll
    for (int kk = 0; kk < 2; ++kk) {
      aOff[f][kk] = rowa * 64 + (((g + kk * 4) ^ (rowa & 7)) << 3);
      bOff[f][kk] = rowb * 64 + (((g + kk * 4) ^ (rowb & 7)) << 3);
    }
  }

  f32x4 acc[4][4] = {};
  bf16x8 ra[4], rb[4];
  {
    long kc = (long)(pcol * 8);
    long ka = (kc >> 6) * p.sAh + (kc & 63);
    #pragma unroll
    for (int c = 0; c < 4; ++c) {
      ra[c] = *(const bf16x8*)(p.A + aRow[c] + ka);
      rb[c] = *(const bf16x8*)(p.B + bRow[c] + kc);
    }
  }

  for (int k0 = 0; k0 < p.K; k0 += 64) {
    __syncthreads();
    #pragma unroll
    for (int c = 0; c < 4; ++c) {
      *(bf16x8*)&As[wIdx[c]] = ra[c];
      *(bf16x8*)&Bs[wIdx[c]] = rb[c];
    }
    __syncthreads();
    if (k0 + 64 < p.K) {
      long kc = (long)(k0 + 64 + pcol * 8);
      long ka = (kc >> 6) * p.sAh + (kc & 63);
      #pragma unroll
      for (int c = 0; c < 4; ++c) {
        ra[c] = *(const bf16x8*)(p.A + aRow[c] + ka);
        rb[c] = *(const bf16x8*)(p.B + bRow[c] + kc);
      }
    }
    #pragma unroll
    for (int kk = 0; kk < 2; ++kk) {
      bf16x8 af[4], bf[4];
      #pragma unroll
      for (int f = 0; f < 4; ++f) {
        af[f] = *(const bf16x8*)&As[aOff[f][kk]];
        bf[f] = *(const bf16x8*)&Bs[bOff[f][kk]];
      }
      #pragma unroll
      for (int i = 0; i < 4; ++i)
        #pragma unroll
        for (int j = 0; j < 4; ++j)
          acc[i][j] = __builtin_amdgcn_mfma_f32_16x16x32_bf16(af[i], bf[j], acc[i][j], 0, 0, 0);
    }
  }

  float bias4[4], aa4[4];
  long ncol[4];
  #pragma unroll
  for (int j = 0; j < 4; ++j) {
    long n = bn + wc * 64 + j * 16 + rA;
    ncol[j] = (n >> 6) * p.sCh + (n & 63);
    bias4[j] = p.hasbias ? p.bias[n] : 0.f;
    aa4[j] = (n < p.alphaN) ? p.alpha : 1.0f;
  }
  #pragma unroll
  for (int i = 0; i < 4; ++i) {
    #pragma unroll
    for (int r = 0; r < 4; ++r) {
      long m = bm + wr * 64 + i * 16 + g * 4 + r;
      long mb = (m >> 11) * p.sCb + (m & 2047) * p.sCt;
      #pragma unroll
      for (int j = 0; j < 4; ++j) {
        long ca = mb + ncol[j];
        float v = aa4[j] * acc[i][j][r] + bias4[j];
        if (p.relu) v = fmaxf(v, 0.f);
        if (p.hasres) v += p.res[ca];
        if (p.cbf16) ((short*)p.C)[ca] = f2bf(v);
        else ((float*)p.C)[ca] = v;
      }
    }
  }
}

// ============================ MFMA flash attention v3 ============================
// QKV packed [B][3][H][T][DH] bf16 (Q pre-scaled by 1/sqrt(T) in GEMM).
// 512 thr (8 waves), 128 q-rows/block, KV tile 64. Defer-max online softmax,
// fused exp2, per-lane partial l (group-reduced once at the end).
__global__ __launch_bounds__(512) void attn_mfma_kernel(const short* __restrict__ qkv,
                                                        short* __restrict__ att) {
  __shared__ __align__(16) short Ks[64 * 64];
  __shared__ __align__(16) short Vt[64 * 64];
  __shared__ __align__(16) short Pq[8 * 16 * 64];

  const int t = threadIdx.x;
  const int lane = t & 63, wid = t >> 6;
  const int wg = xcd_swz(blockIdx.x, gridDim.x);
  const int bh = wg >> 4;                   // 64 (b,h) groups, 16 q-blocks each
  const int b = bh >> 4, h = bh & 15;
  const int q0blk = (wg & 15) * 128;
  const int rA = lane & 15;
  const int g  = lane >> 4;
  const int xq = (rA & 7) << 3;
  const float L2E = 1.4426950408889634f;

  const short* Qg = qkv + (size_t)b * 6291456 + (size_t)h * 131072;
  const short* Kg = Qg + 2097152;
  const short* Vg = Qg + 4194304;

  const int q0w = q0blk + wid * 16;
  bf16x8 qf0 = *(const bf16x8*)(Qg + (size_t)(q0w + rA) * DHEAD + g * 8);
  bf16x8 qf1 = *(const bf16x8*)(Qg + (size_t)(q0w + rA) * DHEAD + 32 + g * 8);

  short* Pw = Pq + wid * 1024;
  const int ss = t >> 3, sp = t & 7;        // staging: row s, chunk sp

  float mrun = -1e30f, lrun = 0.f;
  f32x4 acco[4] = {};

  bf16x8 kreg = *(const bf16x8*)(Kg + (size_t)ss * DHEAD + sp * 8);
  bf16x8 vreg = *(const bf16x8*)(Vg + (size_t)ss * DHEAD + sp * 8);

  for (int tile = 0; tile < T_SEQ / 64; ++tile) {
    __syncthreads();
    *(bf16x8*)&Ks[ss * 64 + ((sp ^ (ss & 7)) << 3)] = kreg;
    #pragma unroll
    for (int j = 0; j < 8; ++j) {           // skewed V^T scalar writes (2-way max)
      int d = sp * 8 + j;
      Vt[d * 64 + ((ss + 8 * (sp + j)) & 63)] = vreg[j];
    }
    __syncthreads();
    if (tile + 1 < T_SEQ / 64) {
      kreg = *(const bf16x8*)(Kg + (size_t)((tile + 1) * 64 + ss) * DHEAD + sp * 8);
      vreg = *(const bf16x8*)(Vg + (size_t)((tile + 1) * 64 + ss) * DHEAD + sp * 8);
    }

    // ---- QK^T: S^T[s][q] (Q pre-scaled) ----
    f32x4 accs[4];
    __builtin_amdgcn_s_setprio(1);
    #pragma unroll
    for (int st = 0; st < 4; ++st) {
      int srow = st * 16 + rA;
      bf16x8 kf0 = *(const bf16x8*)&Ks[srow * 64 + ((g ^ (rA & 7)) << 3)];
      bf16x8 kf1 = *(const bf16x8*)&Ks[srow * 64 + (((g + 4) ^ (rA & 7)) << 3)];
      f32x4 z = {};
      z = __builtin_amdgcn_mfma_f32_16x16x32_bf16(kf0, qf0, z, 0, 0, 0);
      accs[st] = __builtin_amdgcn_mfma_f32_16x16x32_bf16(kf1, qf1, z, 0, 0, 0);
    }
    __builtin_amdgcn_s_setprio(0);

    // ---- tile max (per q = rA, reduced over the 4-lane g-group) ----
    float tm = accs[0][0];
    #pragma unroll
    for (int st = 0; st < 4; ++st)
      #pragma unroll
      for (int r = 0; r < 4; ++r) tm = fmaxf(tm, accs[st][r]);
    tm = fmaxf(tm, __shfl_xor(tm, 16));
    tm = fmaxf(tm, __shfl_xor(tm, 32));

    float pv[16];
    if (__all(tm - mrun <= 8.0f)) {
      // defer-max: keep old m, values bounded by e^8 (bf16/f32 tolerate)
      float mL = mrun * L2E;
      float ts = 0.f;
      #pragma unroll
      for (int st = 0; st < 4; ++st)
        #pragma unroll
        for (int r = 0; r < 4; ++r) {
          float e = EXP2(fmaf(accs[st][r], L2E, -mL));
          pv[st * 4 + r] = e;
          ts += e;
        }
      lrun += ts;                            // per-lane partial l
    } else {
      float mnew = fmaxf(mrun, tm);
      float mL = mnew * L2E;
      float corr = EXP2((mrun - mnew) * L2E);
      float ts = 0.f;
      #pragma unroll
      for (int st = 0; st < 4; ++st)
        #pragma unroll
        for (int r = 0; r < 4; ++r) {
          float e = EXP2(fmaf(accs[st][r], L2E, -mL));
          pv[st * 4 + r] = e;
          ts += e;
        }
      lrun = lrun * corr + ts;
      mrun = mnew;
      float c4r[4];
      #pragma unroll
      for (int r = 0; r < 4; ++r) c4r[r] = __shfl(corr, g * 4 + r);
      #pragma unroll
      for (int dt = 0; dt < 4; ++dt)
        #pragma unroll
        for (int r = 0; r < 4; ++r) acco[dt][r] *= c4r[r];
    }

    // ---- P^T into wave-private swizzled Pq[q][s] ----
    #pragma unroll
    for (int st = 0; st < 4; ++st) {
      short4v pk;
      pk.x = f2bf(pv[st * 4 + 0]);
      pk.y = f2bf(pv[st * 4 + 1]);
      pk.z = f2bf(pv[st * 4 + 2]);
      pk.w = f2bf(pv[st * 4 + 3]);
      *(short4v*)&Pw[(rA * 64 + st * 16 + g * 4) ^ xq] = pk;
    }
    asm volatile("s_waitcnt lgkmcnt(0)" ::: "memory");

    // ---- PV ----
    __builtin_amdgcn_s_setprio(1);
    #pragma unroll
    for (int sk = 0; sk < 2; ++sk) {
      bf16x8 pf = *(const bf16x8*)&Pw[(rA * 64 + sk * 32 + g * 8) ^ xq];
      #pragma unroll
      for (int dt = 0; dt < 4; ++dt) {
        int d = dt * 16 + rA;
        bf16x8 vf = *(const bf16x8*)&Vt[d * 64 +
            ((sk * 32 + g * 8 + 8 * (dt * 2 + (rA >> 3) + (rA & 7))) & 63)];
        acco[dt] = __builtin_amdgcn_mfma_f32_16x16x32_bf16(pf, vf, acco[dt], 0, 0, 0);
      }
    }
    __builtin_amdgcn_s_setprio(0);
  }

  // final l: sum partials across the 4-lane group, then broadcast per output row
  lrun += __shfl_xor(lrun, 16);
  lrun += __shfl_xor(lrun, 32);
  float l4[4];
  #pragma unroll
  for (int r = 0; r < 4; ++r) l4[r] = 1.0f / __shfl(lrun, g * 4 + r);
  #pragma unroll
  for (int dt = 0; dt < 4; ++dt)
    #pragma unroll
    for (int r = 0; r < 4; ++r)
      att[(size_t)bh * T_SEQ * DHEAD + (size_t)(q0w + g * 4 + r) * DHEAD + dt * 16 + rA] =
          f2bf(acco[dt][r] * l4[r]);
}

// ============================ head ============================
__global__ __launch_bounds__(256) void head_kernel(const short* __restrict__ h,
    const float* __restrict__ Wu, const float* __restrict__ bu, float* __restrict__ out) {
  __shared__ float sm[8];
  int row = blockIdx.x;
  const short* hr = h + (size_t)row * E_DIM;
  float a0 = 0.f, a1 = 0.f;
  for (int i = threadIdx.x; i < E_DIM; i += 256) {
    float hv = bf2f(hr[i]);
    a0 = fmaf(hv, Wu[i * 2 + 0], a0);
    a1 = fmaf(hv, Wu[i * 2 + 1], a1);
  }
  #pragma unroll
  for (int off = 32; off; off >>= 1) {
    a0 += __shfl_xor(a0, off, 64);
    a1 += __shfl_xor(a1, off, 64);
  }
  int lane = threadIdx.x & 63, wid = threadIdx.x >> 6;
  if (lane == 0) { sm[wid] = a0; sm[4 + wid] = a1; }
  __syncthreads();
  if (threadIdx.x == 0) {
    out[row * 2 + 0] = sm[0] + sm[1] + sm[2] + sm[3] + bu[0];
    out[row * 2 + 1] = sm[4] + sm[5] + sm[6] + sm[7] + bu[1];
  }
}

// ============================ launcher ============================
static inline void launch_gemm(hipStream_t stream, int N,
    const short* A, long sAb, long sAt, long sAh,
    const short* B, long sBh, long sBd,
    void* C, long sCb, long sCt, long sCh,
    const float* bias, const float* res, int K, float alpha, int alphaN,
    int relu, int cbf16) {
  GemmP p;
  p.A = A; p.B = B; p.C = C; p.bias = bias; p.res = res;
  p.sAb = sAb; p.sAt = sAt; p.sAh = sAh;
  p.sBh = sBh; p.sBd = sBd;
  p.sCb = sCb; p.sCt = sCt; p.sCh = sCh;
  p.K = K; p.alpha = alpha; p.alphaN = alphaN; p.gridx = N / 128;
  p.relu = relu; p.cbf16 = cbf16;
  p.hasbias = bias != nullptr; p.hasres = res != nullptr;
  int nwg = (N / 128) * ((NB * T_SEQ) / 128);
  gemm_bf16<<<nwg, 256, 0, stream>>>(p);
}

extern "C" void kernel_launch(void* const* d_in, const int* in_sizes, int n_in,
                              void* d_out, int out_size, void* d_ws, size_t ws_size,
                              hipStream_t stream) {
  const int*   tokens = (const int*)d_in[0];
  const float* emb_w  = (const float*)d_in[1];
  const float* pos_w  = (const float*)d_in[2];
  const float* Wq     = (const float*)d_in[3];
  const float* Wk     = (const float*)d_in[4];
  const float* Wv     = (const float*)d_in[5];
  const float* Wo     = (const float*)d_in[6];
  const float* ln1_g  = (const float*)d_in[7];
  const float* ln1_b  = (const float*)d_in[8];
  const float* W1     = (const float*)d_in[9];
  const float* b1     = (const float*)d_in[10];
  const float* W2     = (const float*)d_in[11];
  const float* b2     = (const float*)d_in[12];
  const float* ln2_g  = (const float*)d_in[13];
  const float* ln2_b  = (const float*)d_in[14];
  const float* lnf_g  = (const float*)d_in[15];
  const float* lnf_b  = (const float*)d_in[16];
  const float* Wu     = (const float*)d_in[17];
  const float* bu     = (const float*)d_in[18];
  float* out = (float*)d_out;

  // ---- workspace layout (bytes) ----
  char* ws = (char*)d_ws;
  float* X     = (float*)(ws);                       // 32 MB f32 [B,T,E]
  short* Hb    = (short*)(ws + 33554432);            // 16 MB bf16 (LN out / attn out)
  short* QKVb  = (short*)(ws + 50331648);            // 48 MB bf16 [B][3][H][T][DH]
  short* FFH   = (short*)(ws + 100663296);           // 64 MB bf16 [8192,4096]
  short* WqkvT = (short*)(ws + 167772160);           // 6 MB  [3][16][64][1024]
  short* WoT   = (short*)(ws + 174063616);           // 2 MB  [1024][1024]
  short* W1T   = (short*)(ws + 176160768);           // 8 MB  [4096][1024]
  short* W2T   = (short*)(ws + 184549376);           // 8 MB  [1024][4096]

  const float scale = 0.022097086912079608f;         // 1/sqrt(2048)

  embed_kernel<<<32768, 256, 0, stream>>>(tokens, emb_w, pos_w, X);

  for (int l = 0; l < NLAYER; ++l) {
    PrepP pp;
    pp.s0 = Wq + (size_t)l * 1048576; pp.d0 = WqkvT;
    pp.s1 = Wk + (size_t)l * 1048576; pp.d1 = WqkvT + 1048576;
    pp.s2 = Wv + (size_t)l * 1048576; pp.d2 = WqkvT + 2097152;
    pp.s3 = Wo + (size_t)l * 1048576; pp.d3 = WoT;
    pp.s4 = W1 + (size_t)l * 4194304; pp.d4 = W1T;
    pp.s5 = W2 + (size_t)l * 4194304; pp.d5 = W2T;
    prep_kernel<<<12288, dim3(32, 8), 0, stream>>>(pp);

    ln_bf16_kernel<<<8192, 256, 0, stream>>>(X, ln1_g + l * 1024, ln1_b + l * 1024, Hb);

    // merged QKV: N = 3072 (48 head-blocks), C -> [b][3][h][t][d]; Q cols pre-scaled
    launch_gemm(stream, 3072, Hb, 2097152, 1024, 64, WqkvT, 65536, 1024,
                QKVb, 6291456, 64, 131072, nullptr, nullptr, 1024, scale, 1024, 0, 1);

    attn_mfma_kernel<<<1024, 512, 0, stream>>>(QKVb, Hb);   // att -> Hb

    // Wo: A=att [B,H,T,DH], C=X f32 (+res X)
    launch_gemm(stream, 1024, Hb, 2097152, 64, 131072, WoT, 65536, 1024,
                X, 2097152, 1024, 64, nullptr, X, 1024, 1.0f, 0, 0, 0);

    ln_bf16_kernel<<<8192, 256, 0, stream>>>(X, ln2_g + l * 1024, ln2_b + l * 1024, Hb);

    launch_gemm(stream, 4096, Hb, 2097152, 1024, 64, W1T, 65536, 1024,
                FFH, 8388608, 4096, 64, b1 + (size_t)l * 4096, nullptr, 1024, 1.0f, 0, 1, 1);
    launch_gemm(stream, 1024, FFH, 8388608, 4096, 64, W2T, 262144, 4096,
                X, 2097152, 1024, 64, b2 + (size_t)l * 1024, X, 4096, 1.0f, 0, 0, 0);
  }

  ln_bf16_kernel<<<8192, 256, 0, stream>>>(X, lnf_g, lnf_b, Hb);
  head_kernel<<<8192, 256, 0, stream>>>(Hb, Wu, bu, out);
}